// Round 1
// baseline (186.520 us; speedup 1.0000x reference)
//
#include <hip/hip_runtime.h>

#define NBINS 256

// Order-preserving float->uint encoding: enc is monotone increasing in float order.
__device__ __forceinline__ unsigned enc_f(float f) {
    unsigned u = __float_as_uint(f);
    return (u & 0x80000000u) ? ~u : (u | 0x80000000u);
}
__device__ __forceinline__ float dec_f(unsigned u) {
    unsigned v = (u & 0x80000000u) ? (u & 0x7FFFFFFFu) : ~u;
    return __uint_as_float(v);
}

// ws layout (uint32): [0]=min_enc, [1]=max_enc, [2..2+255]=hist bins
__global__ void hrt_init(unsigned* __restrict__ ws) {
    int i = threadIdx.x;
    if (i == 0) { ws[0] = 0xFFFFFFFFu; ws[1] = 0u; }
    ws[2 + i] = 0u;
}

__global__ void hrt_minmax(const float4* __restrict__ in4, long n4,
                           const float* __restrict__ in, long n,
                           unsigned* __restrict__ ws) {
    float lmin = INFINITY, lmax = -INFINITY;
    long tid = (long)blockIdx.x * blockDim.x + threadIdx.x;
    long stride = (long)gridDim.x * blockDim.x;
    for (long i = tid; i < n4; i += stride) {
        float4 v = in4[i];
        lmin = fminf(lmin, fminf(fminf(v.x, v.y), fminf(v.z, v.w)));
        lmax = fmaxf(lmax, fmaxf(fmaxf(v.x, v.y), fmaxf(v.z, v.w)));
    }
    // scalar tail (n not multiple of 4)
    for (long i = n4 * 4 + tid; i < n; i += stride) {
        float v = in[i];
        lmin = fminf(lmin, v);
        lmax = fmaxf(lmax, v);
    }
    // wave (64-lane) butterfly reduce
    #pragma unroll
    for (int off = 32; off > 0; off >>= 1) {
        lmin = fminf(lmin, __shfl_down(lmin, off));
        lmax = fmaxf(lmax, __shfl_down(lmax, off));
    }
    __shared__ float smin[8], smax[8];
    int wave = threadIdx.x >> 6;
    int lane = threadIdx.x & 63;
    if (lane == 0) { smin[wave] = lmin; smax[wave] = lmax; }
    __syncthreads();
    if (threadIdx.x == 0) {
        int nw = blockDim.x >> 6;
        float bmin = smin[0], bmax = smax[0];
        for (int w = 1; w < nw; ++w) {
            bmin = fminf(bmin, smin[w]);
            bmax = fmaxf(bmax, smax[w]);
        }
        atomicMin(&ws[0], enc_f(bmin));
        atomicMax(&ws[1], enc_f(bmax));
    }
}

__global__ void hrt_hist(const float4* __restrict__ in4, long n4,
                         const float* __restrict__ in, long n,
                         unsigned* __restrict__ ws) {
    // per-wave private histograms (4 waves/block) to reduce LDS atomic contention
    __shared__ unsigned lh[4][NBINS];
    for (int i = threadIdx.x; i < 4 * NBINS; i += blockDim.x)
        ((unsigned*)lh)[i] = 0u;
    __syncthreads();

    float tmin = dec_f(ws[0]);
    float tmax = dec_f(ws[1]);
    float scale = (float)NBINS / (tmax - tmin);

    int wave = threadIdx.x >> 6;
    long tid = (long)blockIdx.x * blockDim.x + threadIdx.x;
    long stride = (long)gridDim.x * blockDim.x;
    for (long i = tid; i < n4; i += stride) {
        float4 v = in4[i];
        float c[4] = {v.x, v.y, v.z, v.w};
        #pragma unroll
        for (int k = 0; k < 4; ++k) {
            int idx = (int)((c[k] - tmin) * scale);
            idx = idx < 0 ? 0 : (idx > NBINS - 1 ? NBINS - 1 : idx);
            atomicAdd(&lh[wave][idx], 1u);
        }
    }
    for (long i = n4 * 4 + tid; i < n; i += stride) {
        int idx = (int)((in[i] - tmin) * scale);
        idx = idx < 0 ? 0 : (idx > NBINS - 1 ? NBINS - 1 : idx);
        atomicAdd(&lh[wave][idx], 1u);
    }
    __syncthreads();
    for (int i = threadIdx.x; i < NBINS; i += blockDim.x) {
        unsigned t = lh[0][i] + lh[1][i] + lh[2][i] + lh[3][i];
        if (t) atomicAdd(&ws[2 + i], t);
    }
}

__global__ void hrt_finalize(const unsigned* __restrict__ ws,
                             float* __restrict__ out) {
    if (threadIdx.x != 0 || blockIdx.x != 0) return;
    float tmin = dec_f(ws[0]);
    float tmax = dec_f(ws[1]);
    // float32 cumsum, same accumulation order as the reference
    float total = 0.0f;
    for (int i = 0; i < NBINS; ++i) total += (float)ws[2 + i];
    float tl = total * (1.0f - 0.99f) / 2.0f;
    float tu = total * (1.0f + 0.99f) / 2.0f;
    int lower = -1, upper = -1;
    float cum = 0.0f;
    for (int i = 0; i < NBINS; ++i) {
        cum += (float)ws[2 + i];
        if (lower < 0 && cum > tl) lower = i;
        if (upper < 0 && cum > tu) upper = i;
    }
    if (lower < 0) lower = 0;  // argmax of all-false -> 0
    if (upper < 0) upper = 0;
    float step = (tmax - tmin) / (float)NBINS;
    out[0] = tmin + step * (float)lower;
    out[1] = tmin + step * (float)upper;
}

extern "C" void kernel_launch(void* const* d_in, const int* in_sizes, int n_in,
                              void* d_out, int out_size, void* d_ws, size_t ws_size,
                              hipStream_t stream) {
    const float* in = (const float*)d_in[0];
    long n = (long)in_sizes[0];
    long n4 = n / 4;
    unsigned* ws = (unsigned*)d_ws;
    float* out = (float*)d_out;

    hrt_init<<<1, NBINS, 0, stream>>>(ws);

    const int threads = 256;
    const int blocks = 2048;  // 256 CUs x 8 blocks, grid-stride
    hrt_minmax<<<blocks, threads, 0, stream>>>((const float4*)in, n4, in, n, ws);
    hrt_hist<<<blocks, threads, 0, stream>>>((const float4*)in, n4, in, n, ws);
    hrt_finalize<<<1, 1, 0, stream>>>(ws, out);
}

// Round 2
// 181.146 us; speedup vs baseline: 1.0297x; 1.0297x over previous
//
#include <hip/hip_runtime.h>

#define NBINS 256
#define NCOPY 32   // bank-striped sub-histogram copies

// Order-preserving float->uint encoding: enc is monotone increasing in float order.
__device__ __forceinline__ unsigned enc_f(float f) {
    unsigned u = __float_as_uint(f);
    return (u & 0x80000000u) ? ~u : (u | 0x80000000u);
}
__device__ __forceinline__ float dec_f(unsigned u) {
    unsigned v = (u & 0x80000000u) ? (u & 0x7FFFFFFFu) : ~u;
    return __uint_as_float(v);
}

// ws layout (uint32): [0]=min_enc, [1]=max_enc, [2..2+255]=hist bins
__global__ void hrt_init(unsigned* __restrict__ ws) {
    int i = threadIdx.x;
    if (i == 0) { ws[0] = 0xFFFFFFFFu; ws[1] = 0u; }
    ws[2 + i] = 0u;
}

__global__ void hrt_minmax(const float4* __restrict__ in4, long n4,
                           const float* __restrict__ in, long n,
                           unsigned* __restrict__ ws) {
    float lmin = INFINITY, lmax = -INFINITY;
    long tid = (long)blockIdx.x * blockDim.x + threadIdx.x;
    long stride = (long)gridDim.x * blockDim.x;
    for (long i = tid; i < n4; i += stride) {
        float4 v = in4[i];
        lmin = fminf(lmin, fminf(fminf(v.x, v.y), fminf(v.z, v.w)));
        lmax = fmaxf(lmax, fmaxf(fmaxf(v.x, v.y), fmaxf(v.z, v.w)));
    }
    for (long i = n4 * 4 + tid; i < n; i += stride) {
        float v = in[i];
        lmin = fminf(lmin, v);
        lmax = fmaxf(lmax, v);
    }
    #pragma unroll
    for (int off = 32; off > 0; off >>= 1) {
        lmin = fminf(lmin, __shfl_down(lmin, off));
        lmax = fmaxf(lmax, __shfl_down(lmax, off));
    }
    __shared__ float smin[8], smax[8];
    int wave = threadIdx.x >> 6;
    int lane = threadIdx.x & 63;
    if (lane == 0) { smin[wave] = lmin; smax[wave] = lmax; }
    __syncthreads();
    if (threadIdx.x == 0) {
        int nw = blockDim.x >> 6;
        float bmin = smin[0], bmax = smax[0];
        for (int w = 1; w < nw; ++w) {
            bmin = fminf(bmin, smin[w]);
            bmax = fmaxf(bmax, smax[w]);
        }
        atomicMin(&ws[0], enc_f(bmin));
        atomicMax(&ws[1], enc_f(bmax));
    }
}

__global__ void hrt_hist(const float4* __restrict__ in4, long n4,
                         const float* __restrict__ in, long n,
                         unsigned* __restrict__ ws) {
    // Bank-striped sub-histograms: bin b, copy c lives at lh[b*32 + c],
    // i.e. bank c. Lane uses c = lane&31 -> every LDS atomic of a wave goes
    // to its own bank (2-way lane aliasing i / i+32 only, which is free).
    __shared__ unsigned lh[NBINS * NCOPY];
    for (int i = threadIdx.x; i < NBINS * NCOPY; i += blockDim.x)
        lh[i] = 0u;
    __syncthreads();

    float tmin = dec_f(ws[0]);
    float tmax = dec_f(ws[1]);
    float scale = (float)NBINS / (tmax - tmin);

    int copy = threadIdx.x & (NCOPY - 1);
    long tid = (long)blockIdx.x * blockDim.x + threadIdx.x;
    long stride = (long)gridDim.x * blockDim.x;
    for (long i = tid; i < n4; i += stride) {
        float4 v = in4[i];
        float c[4] = {v.x, v.y, v.z, v.w};
        #pragma unroll
        for (int k = 0; k < 4; ++k) {
            int idx = (int)((c[k] - tmin) * scale);
            idx = idx < 0 ? 0 : (idx > NBINS - 1 ? NBINS - 1 : idx);
            atomicAdd(&lh[idx * NCOPY + copy], 1u);
        }
    }
    for (long i = n4 * 4 + tid; i < n; i += stride) {
        int idx = (int)((in[i] - tmin) * scale);
        idx = idx < 0 ? 0 : (idx > NBINS - 1 ? NBINS - 1 : idx);
        atomicAdd(&lh[idx * NCOPY + copy], 1u);
    }
    __syncthreads();

    // Reduce 32 copies per bin; rotate copy index by lane so each iteration's
    // 64 reads hit 32 distinct banks (2-way aliasing, free).
    int lane = threadIdx.x & 63;
    for (int b = threadIdx.x; b < NBINS; b += blockDim.x) {
        unsigned t = 0;
        #pragma unroll
        for (int c = 0; c < NCOPY; ++c) {
            int cc = (c + lane) & (NCOPY - 1);
            t += lh[b * NCOPY + cc];
        }
        if (t) atomicAdd(&ws[2 + b], t);
    }
}

__global__ void hrt_finalize(const unsigned* __restrict__ ws,
                             float* __restrict__ out) {
    if (threadIdx.x != 0 || blockIdx.x != 0) return;
    float tmin = dec_f(ws[0]);
    float tmax = dec_f(ws[1]);
    float total = 0.0f;
    for (int i = 0; i < NBINS; ++i) total += (float)ws[2 + i];
    float tl = total * (1.0f - 0.99f) / 2.0f;
    float tu = total * (1.0f + 0.99f) / 2.0f;
    int lower = -1, upper = -1;
    float cum = 0.0f;
    for (int i = 0; i < NBINS; ++i) {
        cum += (float)ws[2 + i];
        if (lower < 0 && cum > tl) lower = i;
        if (upper < 0 && cum > tu) upper = i;
    }
    if (lower < 0) lower = 0;
    if (upper < 0) upper = 0;
    float step = (tmax - tmin) / (float)NBINS;
    out[0] = tmin + step * (float)lower;
    out[1] = tmin + step * (float)upper;
}

extern "C" void kernel_launch(void* const* d_in, const int* in_sizes, int n_in,
                              void* d_out, int out_size, void* d_ws, size_t ws_size,
                              hipStream_t stream) {
    const float* in = (const float*)d_in[0];
    long n = (long)in_sizes[0];
    long n4 = n / 4;
    unsigned* ws = (unsigned*)d_ws;
    float* out = (float*)d_out;

    hrt_init<<<1, NBINS, 0, stream>>>(ws);

    const int threads = 256;
    const int blocks = 2048;  // 256 CUs x 8 blocks, grid-stride
    hrt_minmax<<<blocks, threads, 0, stream>>>((const float4*)in, n4, in, n, ws);
    hrt_hist<<<blocks, threads, 0, stream>>>((const float4*)in, n4, in, n, ws);
    hrt_finalize<<<1, 1, 0, stream>>>(ws, out);
}